// Round 1
// baseline (1516.550 us; speedup 1.0000x reference)
//
#include <hip/hip_runtime.h>

#define Bb 128
#define Nn 4096
#define Ff 32
#define Ee 16
#define Hh 7
#define EH 112
#define NROW (Bb*Nn)
#define W2PAD 116   // LDS row pad for W2T (gcd(116,32)=4 -> good bank spread, 16B aligned)

// ---------------------------------------------------------------- encoder ---
__global__ __launch_bounds__(256) void enc_kernel(
    const float* __restrict__ X,
    const float* __restrict__ W1, const float* __restrict__ b1,
    const float* __restrict__ W2, const float* __restrict__ b2,
    const float* __restrict__ W3, const float* __restrict__ b3,
    const float* __restrict__ g,  const float* __restrict__ be,
    float* __restrict__ Xe, float* __restrict__ Z)
{
    __shared__ float sW1[Ff*Ee], sW2[Ee*Ee], sW3[Ee*Ee];
    __shared__ float sb1[Ee], sb2[Ee], sb3[Ee], sg[Ee], sbe[Ee];
    int tid = threadIdx.x;
    for (int i = tid; i < Ff*Ee; i += 256) sW1[i] = W1[i];
    for (int i = tid; i < Ee*Ee; i += 256) { sW2[i] = W2[i]; sW3[i] = W3[i]; }
    if (tid < Ee) { sb1[tid]=b1[tid]; sb2[tid]=b2[tid]; sb3[tid]=b3[tid];
                    sg[tid]=g[tid];   sbe[tid]=be[tid]; }
    __syncthreads();

    size_t row = (size_t)blockIdx.x * 256u + (unsigned)tid;
    const float4* xr = reinterpret_cast<const float4*>(X + row * Ff);
    float x[Ff];
    #pragma unroll
    for (int i = 0; i < Ff/4; ++i) {
        float4 v = xr[i];
        x[4*i+0]=v.x; x[4*i+1]=v.y; x[4*i+2]=v.z; x[4*i+3]=v.w;
    }
    float h1[Ee];
    #pragma unroll
    for (int e = 0; e < Ee; ++e) h1[e] = sb1[e];
    #pragma unroll 4
    for (int k = 0; k < Ff; ++k) {
        float xk = x[k];
        #pragma unroll
        for (int e = 0; e < Ee; ++e) h1[e] = fmaf(xk, sW1[k*Ee+e], h1[e]);
    }
    #pragma unroll
    for (int e = 0; e < Ee; ++e) h1[e] = fmaxf(h1[e], 0.f);

    float h2[Ee];
    #pragma unroll
    for (int e = 0; e < Ee; ++e) h2[e] = sb2[e];
    #pragma unroll 4
    for (int k = 0; k < Ee; ++k) {
        float hk = h1[k];
        #pragma unroll
        for (int e = 0; e < Ee; ++e) h2[e] = fmaf(hk, sW2[k*Ee+e], h2[e]);
    }
    #pragma unroll
    for (int e = 0; e < Ee; ++e) h2[e] = fmaxf(h2[e], 0.f);

    float z[Ee];
    #pragma unroll
    for (int e = 0; e < Ee; ++e) z[e] = sb3[e];
    #pragma unroll 4
    for (int k = 0; k < Ee; ++k) {
        float hk = h2[k];
        #pragma unroll
        for (int e = 0; e < Ee; ++e) z[e] = fmaf(hk, sW3[k*Ee+e], z[e]);
    }
    // LayerNorm over 16
    float m = 0.f;
    #pragma unroll
    for (int e = 0; e < Ee; ++e) m += z[e];
    m *= (1.f/Ee);
    float v = 0.f;
    #pragma unroll
    for (int e = 0; e < Ee; ++e) { float d = z[e]-m; v += d*d; }
    v *= (1.f/Ee);
    float inv = rsqrtf(v + 1e-6f);
    #pragma unroll
    for (int e = 0; e < Ee; ++e) z[e] = (z[e]-m)*inv*sg[e] + sbe[e];

    float4* xo = reinterpret_cast<float4*>(Xe + row*Ee);
    float4* zo = reinterpret_cast<float4*>(Z  + row*Ee);
    #pragma unroll
    for (int i = 0; i < Ee/4; ++i) {
        float4 o; o.x=z[4*i]; o.y=z[4*i+1]; o.z=z[4*i+2]; o.w=z[4*i+3];
        xo[i] = o; zo[i] = o;
    }
}

// ------------------------------------------------------------------- Zbar ---
__global__ __launch_bounds__(512) void zbar_kernel(
    const float* __restrict__ Z, const int* __restrict__ avail,
    const float* __restrict__ Wagg, const float* __restrict__ bagg,
    float* __restrict__ Zbar)
{
    __shared__ float sW[Ee*Hh];
    __shared__ float sb[Hh];
    __shared__ float red[512][8];
    int b = blockIdx.x;
    int tid = threadIdx.x;
    if (tid < Ee*Hh) sW[tid] = Wagg[tid];
    if (tid < Hh)    sb[tid] = bagg[tid];
    __syncthreads();

    float acc[Hh]; float cnt = 0.f;
    #pragma unroll
    for (int h = 0; h < Hh; ++h) acc[h] = 0.f;

    for (int n = tid; n < Nn; n += 512) {
        size_t row = (size_t)b*Nn + n;
        const float4* zr = reinterpret_cast<const float4*>(Z + row*Ee);
        float zs[Ee];
        #pragma unroll
        for (int i = 0; i < Ee/4; ++i) {
            float4 v = zr[i];
            zs[4*i+0]=v.x*v.x; zs[4*i+1]=v.y*v.y; zs[4*i+2]=v.z*v.z; zs[4*i+3]=v.w*v.w;
        }
        float fc[Hh];
        #pragma unroll
        for (int h = 0; h < Hh; ++h) fc[h] = sb[h];
        #pragma unroll 4
        for (int e = 0; e < Ee; ++e) {
            float ze = zs[e];
            #pragma unroll
            for (int h = 0; h < Hh; ++h) fc[h] = fmaf(ze, sW[e*Hh+h], fc[h]);
        }
        float af = (float)avail[(size_t)b*Nn + n];
        #pragma unroll
        for (int h = 0; h < Hh; ++h) acc[h] = fmaf(af, fc[h], acc[h]);
        cnt += af;
    }
    #pragma unroll
    for (int h = 0; h < Hh; ++h) red[tid][h] = acc[h];
    red[tid][7] = cnt;
    __syncthreads();
    for (int s = 256; s > 0; s >>= 1) {
        if (tid < s) {
            #pragma unroll
            for (int i = 0; i < 8; ++i) red[tid][i] += red[tid+s][i];
        }
        __syncthreads();
    }
    if (tid < Hh) Zbar[b*Hh + tid] = red[0][tid] / fmaxf(red[0][7], 1.0f);
}

// -------------------------------------------------------- phi + delta (+proj)
template<bool LAST>
__global__ __launch_bounds__(256) void phi_kernel(
    const float* __restrict__ Xe, float* __restrict__ Z,
    const float* __restrict__ Zbar,
    const float* __restrict__ W1g, const float* __restrict__ b1g,
    const float* __restrict__ W2g, const float* __restrict__ b2g,
    const float* __restrict__ gg,  const float* __restrict__ beg,
    const float* __restrict__ Wp,  const float* __restrict__ bp,
    float* __restrict__ out)
{
    __shared__ float sW2T[EH][W2PAD];     // W2 transposed: [j][k]
    __shared__ float sb1[EH], sb2[EH], sg[EH], sbe[EH];
    __shared__ float sphi1[4][4][EH];     // [wave][r][k]
    __shared__ float sx[4][4][Ee];        // [wave][r][e]

    int tid = threadIdx.x;
    for (int i = tid; i < EH*EH; i += 256) {
        int k = i / EH, j = i - k*EH;
        sW2T[j][k] = W2g[i];
    }
    if (tid < EH) { sb1[tid]=b1g[tid]; sb2[tid]=b2g[tid]; sg[tid]=gg[tid]; sbe[tid]=beg[tid]; }
    __syncthreads();

    int wave = tid >> 6, lane = tid & 63;
    int j0 = lane;
    int j1 = lane + 64;
    bool has1 = (j1 < EH);
    int j1c = has1 ? j1 : 0;

    float wp0 = 0.f, wp1 = 0.f, bp0 = 0.f, bp1 = 0.f;
    if (LAST) {
        wp0 = Wp[(lane & 15)*2 + 0];
        wp1 = Wp[(lane & 15)*2 + 1];
        bp0 = bp[0]; bp1 = bp[1];
    }

    int gw = blockIdx.x*4 + wave;
    int nchunks = NROW/4;
    int stride = gridDim.x * 4;
    for (int c = gw; c < nchunks; c += stride) {
        size_t row0 = (size_t)c * 4;
        int b = (int)(row0 >> 12);      // N = 4096 rows per batch

        float zb0 = Zbar[b*Hh + (lane >> 4)] * (1.f/Hh);
        float zb1 = Zbar[b*Hh + (has1 ? 4 + (lane >> 4) : 0)] * (1.f/Hh);

        // stage 4 rows of X_embd (16 f32 each) into LDS
        if (lane < 16) {
            int r = lane >> 2, q = lane & 3;
            float4 vv = *reinterpret_cast<const float4*>(Xe + (row0 + r)*Ee + q*4);
            *reinterpret_cast<float4*>(&sx[wave][r][q*4]) = vv;
        }

        // ---- phi1 = relu(x @ W1 + b1) : 2 cols per lane, 4 rows
        float p1a[4], p1b[4];
        #pragma unroll
        for (int r = 0; r < 4; ++r) { p1a[r] = sb1[j0]; p1b[r] = sb1[j1c]; }
        #pragma unroll 4
        for (int e = 0; e < Ee; ++e) {
            float w0 = W1g[e*EH + j0];
            float w1 = W1g[e*EH + j1c];
            #pragma unroll
            for (int r = 0; r < 4; ++r) {
                float xv = sx[wave][r][e];
                p1a[r] = fmaf(xv, w0, p1a[r]);
                p1b[r] = fmaf(xv, w1, p1b[r]);
            }
        }
        #pragma unroll
        for (int r = 0; r < 4; ++r) {
            p1a[r] = fmaxf(p1a[r], 0.f);
            p1b[r] = fmaxf(p1b[r], 0.f);
            sphi1[wave][r][j0] = p1a[r];
            if (has1) sphi1[wave][r][j1] = p1b[r];
        }

        // ---- phi2 = phi1 @ W2 + b2
        float a0[4], a1[4];
        #pragma unroll
        for (int r = 0; r < 4; ++r) { a0[r] = sb2[j0]; a1[r] = sb2[j1c]; }
        for (int kk = 0; kk < EH; kk += 4) {
            float4 w0 = *reinterpret_cast<const float4*>(&sW2T[j0][kk]);
            float4 w1 = *reinterpret_cast<const float4*>(&sW2T[j1c][kk]);
            #pragma unroll
            for (int r = 0; r < 4; ++r) {
                float4 p = *reinterpret_cast<const float4*>(&sphi1[wave][r][kk]);
                a0[r] = fmaf(p.x, w0.x, a0[r]); a0[r] = fmaf(p.y, w0.y, a0[r]);
                a0[r] = fmaf(p.z, w0.z, a0[r]); a0[r] = fmaf(p.w, w0.w, a0[r]);
                a1[r] = fmaf(p.x, w1.x, a1[r]); a1[r] = fmaf(p.y, w1.y, a1[r]);
                a1[r] = fmaf(p.z, w1.z, a1[r]); a1[r] = fmaf(p.w, w1.w, a1[r]);
            }
        }

        // ---- LayerNorm over 112 + delta + Z update (+ fused projection)
        #pragma unroll
        for (int r = 0; r < 4; ++r) {
            float v0 = a0[r], v1 = a1[r];
            float s = v0 + (has1 ? v1 : 0.f);
            #pragma unroll
            for (int off = 1; off < 64; off <<= 1) s += __shfl_xor(s, off);
            float m = s * (1.f/EH);
            float d0 = v0 - m, d1 = v1 - m;
            float q = d0*d0 + (has1 ? d1*d1 : 0.f);
            #pragma unroll
            for (int off = 1; off < 64; off <<= 1) q += __shfl_xor(q, off);
            float inv = rsqrtf(q*(1.f/EH) + 1e-6f);
            float ph0 = d0*inv*sg[j0]  + sbe[j0];
            float ph1 = d1*inv*sg[j1c] + sbe[j1c];

            // delta[e] = sum_h phi[h*16+e]*Zbar[h]/H ; j=h*16+e -> h=j>>4, e=j&15
            float t = ph0*zb0 + (has1 ? ph1*zb1 : 0.f);
            t += __shfl_xor(t, 16);
            t += __shfl_xor(t, 32);   // now every lane holds delta[e = lane&15]

            float znew = Z[(row0 + r)*Ee + (lane & 15)] + t;

            if (LAST) {
                float po0 = znew * wp0;
                float po1 = znew * wp1;
                #pragma unroll
                for (int off = 1; off < 16; off <<= 1) {
                    po0 += __shfl_xor(po0, off);
                    po1 += __shfl_xor(po1, off);
                }
                if (lane == 0) {
                    float2 o; o.x = po0 + bp0; o.y = po1 + bp1;
                    *reinterpret_cast<float2*>(out + (row0 + r)*2) = o;
                }
            } else {
                if (lane < Ee) Z[(row0 + r)*Ee + lane] = znew;
            }
        }
    }
}

// ---------------------------------------------------------------- launcher --
extern "C" void kernel_launch(void* const* d_in, const int* in_sizes, int n_in,
                              void* d_out, int out_size, void* d_ws, size_t ws_size,
                              hipStream_t stream)
{
    const float* X      = (const float*)d_in[0];
    const int*   avail  = (const int*)  d_in[1];
    const float* W_enc1 = (const float*)d_in[2];  const float* b_enc1 = (const float*)d_in[3];
    const float* W_enc2 = (const float*)d_in[4];  const float* b_enc2 = (const float*)d_in[5];
    const float* W_enc3 = (const float*)d_in[6];  const float* b_enc3 = (const float*)d_in[7];
    const float* g_enc  = (const float*)d_in[8];  const float* be_enc = (const float*)d_in[9];
    const float* W_agg  = (const float*)d_in[10]; const float* b_agg  = (const float*)d_in[11];
    const float* W_phi1 = (const float*)d_in[12]; const float* b_phi1 = (const float*)d_in[13];
    const float* W_phi2 = (const float*)d_in[14]; const float* b_phi2 = (const float*)d_in[15];
    const float* g_phi  = (const float*)d_in[16]; const float* be_phi = (const float*)d_in[17];
    const float* W_proj = (const float*)d_in[18]; const float* b_proj = (const float*)d_in[19];
    float* out = (float*)d_out;

    float* Xe = (float*)d_ws;                       // [NROW][16]  32 MB
    float* Z  = Xe + (size_t)NROW * Ee;             // [NROW][16]  32 MB
    float* Zb = Z  + (size_t)NROW * Ee;             // [128][7]

    enc_kernel<<<NROW/256, 256, 0, stream>>>(
        X, W_enc1, b_enc1, W_enc2, b_enc2, W_enc3, b_enc3, g_enc, be_enc, Xe, Z);

    for (int d = 0; d < 3; ++d) {
        zbar_kernel<<<Bb, 512, 0, stream>>>(
            Z, avail, W_agg + d*Ee*Hh, b_agg + d*Hh, Zb);
        if (d < 2) {
            phi_kernel<false><<<512, 256, 0, stream>>>(
                Xe, Z, Zb,
                W_phi1 + d*Ee*EH, b_phi1 + d*EH,
                W_phi2 + d*EH*EH, b_phi2 + d*EH,
                g_phi + d*EH, be_phi + d*EH, W_proj, b_proj, out);
        } else {
            phi_kernel<true><<<512, 256, 0, stream>>>(
                Xe, Z, Zb,
                W_phi1 + d*Ee*EH, b_phi1 + d*EH,
                W_phi2 + d*EH*EH, b_phi2 + d*EH,
                g_phi + d*EH, be_phi + d*EH, W_proj, b_proj, out);
        }
    }
}

// Round 2
// 523.902 us; speedup vs baseline: 2.8947x; 2.8947x over previous
//
#include <hip/hip_runtime.h>
#include <hip/hip_bf16.h>

#define Bb 128
#define Nn 4096
#define Ff 32
#define Ee 16
#define Hh 7
#define EH 112
#define NROW (Bb*Nn)
#define PS 136              // ushort stride of per-wave phi1 LDS row (272 B, 16B-aligned)
#define TPB_TILES 16        // 16-row tiles per block
#define NBLK (NROW/16/TPB_TILES)   // 2048 blocks

typedef __attribute__((ext_vector_type(8))) short  bf16x8;
typedef __attribute__((ext_vector_type(4))) float  f32x4;
typedef __attribute__((ext_vector_type(4))) unsigned int u32x4;
typedef __attribute__((ext_vector_type(2))) unsigned int u32x2;

__device__ inline unsigned pack2(float a, float b) {
    __hip_bfloat162 h = __float22bfloat162_rn(make_float2(a, b));
    return *reinterpret_cast<unsigned*>(&h);
}
union BF8 { unsigned u[4]; bf16x8 v; u32x4 q; };

// ---------------------------------------------------------------- encoder ---
__global__ __launch_bounds__(256) void enc_kernel(
    const float* __restrict__ X,
    const float* __restrict__ W1, const float* __restrict__ b1,
    const float* __restrict__ W2, const float* __restrict__ b2,
    const float* __restrict__ W3, const float* __restrict__ b3,
    const float* __restrict__ g,  const float* __restrict__ be,
    unsigned short* __restrict__ XeBF, float* __restrict__ Z)
{
    __shared__ float sW1[Ff*Ee], sW2[Ee*Ee], sW3[Ee*Ee];
    __shared__ float sb1[Ee], sb2[Ee], sb3[Ee], sg[Ee], sbe[Ee];
    int tid = threadIdx.x;
    for (int i = tid; i < Ff*Ee; i += 256) sW1[i] = W1[i];
    for (int i = tid; i < Ee*Ee; i += 256) { sW2[i] = W2[i]; sW3[i] = W3[i]; }
    if (tid < Ee) { sb1[tid]=b1[tid]; sb2[tid]=b2[tid]; sb3[tid]=b3[tid];
                    sg[tid]=g[tid];   sbe[tid]=be[tid]; }
    __syncthreads();

    size_t row = (size_t)blockIdx.x * 256u + (unsigned)tid;
    const float4* xr = reinterpret_cast<const float4*>(X + row * Ff);
    float x[Ff];
    #pragma unroll
    for (int i = 0; i < Ff/4; ++i) {
        float4 v = xr[i];
        x[4*i+0]=v.x; x[4*i+1]=v.y; x[4*i+2]=v.z; x[4*i+3]=v.w;
    }
    float h1[Ee];
    #pragma unroll
    for (int e = 0; e < Ee; ++e) h1[e] = sb1[e];
    #pragma unroll 4
    for (int k = 0; k < Ff; ++k) {
        float xk = x[k];
        #pragma unroll
        for (int e = 0; e < Ee; ++e) h1[e] = fmaf(xk, sW1[k*Ee+e], h1[e]);
    }
    #pragma unroll
    for (int e = 0; e < Ee; ++e) h1[e] = fmaxf(h1[e], 0.f);

    float h2[Ee];
    #pragma unroll
    for (int e = 0; e < Ee; ++e) h2[e] = sb2[e];
    #pragma unroll 4
    for (int k = 0; k < Ee; ++k) {
        float hk = h1[k];
        #pragma unroll
        for (int e = 0; e < Ee; ++e) h2[e] = fmaf(hk, sW2[k*Ee+e], h2[e]);
    }
    #pragma unroll
    for (int e = 0; e < Ee; ++e) h2[e] = fmaxf(h2[e], 0.f);

    float z[Ee];
    #pragma unroll
    for (int e = 0; e < Ee; ++e) z[e] = sb3[e];
    #pragma unroll 4
    for (int k = 0; k < Ee; ++k) {
        float hk = h2[k];
        #pragma unroll
        for (int e = 0; e < Ee; ++e) z[e] = fmaf(hk, sW3[k*Ee+e], z[e]);
    }
    float m = 0.f;
    #pragma unroll
    for (int e = 0; e < Ee; ++e) m += z[e];
    m *= (1.f/Ee);
    float v = 0.f;
    #pragma unroll
    for (int e = 0; e < Ee; ++e) { float d = z[e]-m; v += d*d; }
    v *= (1.f/Ee);
    float inv = rsqrtf(v + 1e-6f);
    #pragma unroll
    for (int e = 0; e < Ee; ++e) z[e] = (z[e]-m)*inv*sg[e] + sbe[e];

    // Z in f32
    float4* zo = reinterpret_cast<float4*>(Z + row*Ee);
    #pragma unroll
    for (int i = 0; i < Ee/4; ++i) {
        float4 o; o.x=z[4*i]; o.y=z[4*i+1]; o.z=z[4*i+2]; o.w=z[4*i+3];
        zo[i] = o;
    }
    // X_embd in bf16
    unsigned us[8];
    #pragma unroll
    for (int j = 0; j < 8; ++j) us[j] = pack2(z[2*j], z[2*j+1]);
    u32x4 lo = {us[0],us[1],us[2],us[3]};
    u32x4 hi = {us[4],us[5],us[6],us[7]};
    u32x4* xo = reinterpret_cast<u32x4*>(XeBF + row*Ee);
    xo[0] = lo; xo[1] = hi;
}

// ------------------------------------------------------------------- Zbar ---
__global__ __launch_bounds__(512) void zbar_kernel(
    const float* __restrict__ Z, const int* __restrict__ avail,
    const float* __restrict__ Wagg, const float* __restrict__ bagg,
    float* __restrict__ Zbar)
{
    __shared__ float sW[Ee*Hh];
    __shared__ float sb[Hh];
    __shared__ float red[512][8];
    int b = blockIdx.x;
    int tid = threadIdx.x;
    if (tid < Ee*Hh) sW[tid] = Wagg[tid];
    if (tid < Hh)    sb[tid] = bagg[tid];
    __syncthreads();

    float acc[Hh]; float cnt = 0.f;
    #pragma unroll
    for (int h = 0; h < Hh; ++h) acc[h] = 0.f;

    for (int n = tid; n < Nn; n += 512) {
        size_t row = (size_t)b*Nn + n;
        const float4* zr = reinterpret_cast<const float4*>(Z + row*Ee);
        float zs[Ee];
        #pragma unroll
        for (int i = 0; i < Ee/4; ++i) {
            float4 v = zr[i];
            zs[4*i+0]=v.x*v.x; zs[4*i+1]=v.y*v.y; zs[4*i+2]=v.z*v.z; zs[4*i+3]=v.w*v.w;
        }
        float fc[Hh];
        #pragma unroll
        for (int h = 0; h < Hh; ++h) fc[h] = sb[h];
        #pragma unroll 4
        for (int e = 0; e < Ee; ++e) {
            float ze = zs[e];
            #pragma unroll
            for (int h = 0; h < Hh; ++h) fc[h] = fmaf(ze, sW[e*Hh+h], fc[h]);
        }
        float af = (float)avail[(size_t)b*Nn + n];
        #pragma unroll
        for (int h = 0; h < Hh; ++h) acc[h] = fmaf(af, fc[h], acc[h]);
        cnt += af;
    }
    #pragma unroll
    for (int h = 0; h < Hh; ++h) red[tid][h] = acc[h];
    red[tid][7] = cnt;
    __syncthreads();
    for (int s = 256; s > 0; s >>= 1) {
        if (tid < s) {
            #pragma unroll
            for (int i = 0; i < 8; ++i) red[tid][i] += red[tid+s][i];
        }
        __syncthreads();
    }
    if (tid < Hh) Zbar[b*Hh + tid] = red[0][tid] / fmaxf(red[0][7], 1.0f);
}

// ---------------------------------------------------- phi via MFMA (+proj) --
template<bool LAST>
__global__ __launch_bounds__(256, 2) void phi_mfma(
    const unsigned short* __restrict__ Xe,   // bf16 [NROW][16]
    float* __restrict__ Z,
    const float* __restrict__ Zbar,
    const float* __restrict__ W1g, const float* __restrict__ b1g,
    const float* __restrict__ W2g, const float* __restrict__ b2g,
    const float* __restrict__ gg,  const float* __restrict__ beg,
    const float* __restrict__ Wp,  const float* __restrict__ bp,
    float* __restrict__ out)
{
    // W2^T fragments, pre-packed in MFMA A-frag order: frag f=(mt*4+kt), 64 lanes x 8 bf16
    __shared__ __align__(16) unsigned short sW2F[28*512];
    // per-wave phi1 tile [16 rows][PS cols] bf16 (cols 112..135 stay zero = K-pad)
    __shared__ __align__(16) unsigned short sP1[4][16*PS];

    int tid  = threadIdx.x;
    int wave = tid >> 6, lane = tid & 63;
    int g = lane >> 4, i = lane & 15;

    // ---- stage W2^T fragments (bf16) ----
    for (int p = tid; p < 28*64; p += 256) {
        int f = p >> 6, l = p & 63;
        int lg = l >> 4, li = l & 15;
        int mt = f >> 2, kt = f & 3;
        unsigned v[4];
        #pragma unroll
        for (int jj = 0; jj < 4; ++jj) {
            int k0 = kt*32 + lg*8 + jj*2;
            float a = (k0   < EH) ? W2g[(size_t)k0*EH     + mt*16 + li] : 0.f;
            float c = (k0+1 < EH) ? W2g[(size_t)(k0+1)*EH + mt*16 + li] : 0.f;
            v[jj] = pack2(a, c);
        }
        u32x4 q = {v[0], v[1], v[2], v[3]};
        *reinterpret_cast<u32x4*>(&sW2F[f*512 + l*8]) = q;
    }
    // ---- zero sP1 (covers the k=112..127 pad forever) ----
    for (int p = tid; p < (4*16*PS)/8; p += 256) {
        u32x4 zq = {0u,0u,0u,0u};
        reinterpret_cast<u32x4*>(&sP1[0][0])[p] = zq;
    }

    // ---- per-batch / per-depth constants (block stays within one batch) ----
    int b = blockIdx.x / (Nn / (TPB_TILES*16));    // 16 blocks per batch
    float zb[Hh];
    #pragma unroll
    for (int mt = 0; mt < Hh; ++mt) zb[mt] = Zbar[b*Hh + mt] * (1.f/Hh);

    f32x4 pb1[7], pb2[7], gz[7];
    float Gz[4] = {0,0,0,0}, Bz[4] = {0,0,0,0};
    #pragma unroll
    for (int mt = 0; mt < 7; ++mt) {
        pb1[mt] = *reinterpret_cast<const f32x4*>(b1g + mt*16 + 4*g);
        pb2[mt] = *reinterpret_cast<const f32x4*>(b2g + mt*16 + 4*g);
        f32x4 pg = *reinterpret_cast<const f32x4*>(gg  + mt*16 + 4*g);
        f32x4 pe = *reinterpret_cast<const f32x4*>(beg + mt*16 + 4*g);
        #pragma unroll
        for (int r = 0; r < 4; ++r) {
            float gzv = pg[r] * zb[mt];
            gz[mt][r] = gzv;
            Gz[r] += gzv;
            Bz[r] += pe[r] * zb[mt];
        }
    }
    // W1^T A-fragments (zero-padded k>=16)
    bf16x8 aW1[7];
    #pragma unroll
    for (int mt = 0; mt < 7; ++mt) {
        BF8 c;
        #pragma unroll
        for (int jj = 0; jj < 4; ++jj) {
            float a = 0.f, d = 0.f;
            if (g < 2) {
                a = W1g[(size_t)(g*8 + jj*2)  *EH + mt*16 + i];
                d = W1g[(size_t)(g*8 + jj*2+1)*EH + mt*16 + i];
            }
            c.u[jj] = pack2(a, d);
        }
        aW1[mt] = c.v;
    }
    float wpa[4] = {0,0,0,0}, wpb[4] = {0,0,0,0}, bp0 = 0.f, bp1 = 0.f;
    if (LAST) {
        f32x4 u0 = *reinterpret_cast<const f32x4*>(Wp + 8*g);
        f32x4 u1 = *reinterpret_cast<const f32x4*>(Wp + 8*g + 4);
        wpa[0]=u0[0]; wpa[1]=u0[2]; wpa[2]=u1[0]; wpa[3]=u1[2];
        wpb[0]=u0[1]; wpb[1]=u0[3]; wpb[2]=u1[1]; wpb[3]=u1[3];
        bp0 = bp[0]; bp1 = bp[1];
    }
    __syncthreads();

    unsigned short* myP1 = &sP1[wave][0];

    #pragma unroll 1
    for (int t = 0; t < TPB_TILES/4; ++t) {
        int tile = blockIdx.x*TPB_TILES + t*4 + wave;
        size_t row0 = (size_t)tile * 16;

        // B-frag of phi1 MFMA: Xe rows, k=feature (groups 2,3 = zero pad)
        BF8 bxz; bxz.u[0]=bxz.u[1]=bxz.u[2]=bxz.u[3]=0u;
        bf16x8 bx = bxz.v;
        if (g < 2)
            bx = *reinterpret_cast<const bf16x8*>(Xe + (row0 + i)*Ee + g*8);
        // Z preload for epilogue
        f32x4 zv = *reinterpret_cast<const f32x4*>(Z + (row0 + i)*Ee + 4*g);

        // ---- phi1^T = W1^T @ Xe^T (7 MFMAs), relu, pack, stash in LDS ----
        #pragma unroll
        for (int mt = 0; mt < 7; ++mt) {
            f32x4 d = __builtin_amdgcn_mfma_f32_16x16x32_bf16(aW1[mt], bx, pb1[mt], 0, 0, 0);
            #pragma unroll
            for (int r = 0; r < 4; ++r) d[r] = fmaxf(d[r], 0.f);
            u32x2 w = {pack2(d[0], d[1]), pack2(d[2], d[3])};
            *reinterpret_cast<u32x2*>(&myP1[i*PS + mt*16 + 4*g]) = w;
        }

        // ---- phi2^T = W2^T @ phi1^T (28 MFMAs) ----
        f32x4 d2[7];
        #pragma unroll
        for (int mt = 0; mt < 7; ++mt) d2[mt] = pb2[mt];
        #pragma unroll
        for (int kt = 0; kt < 4; ++kt) {
            bf16x8 bpv = *reinterpret_cast<const bf16x8*>(&myP1[i*PS + kt*32 + 8*g]);
            #pragma unroll
            for (int mt = 0; mt < 7; ++mt) {
                bf16x8 a = *reinterpret_cast<const bf16x8*>(&sW2F[(mt*4 + kt)*512 + lane*8]);
                d2[mt] = __builtin_amdgcn_mfma_f32_16x16x32_bf16(a, bpv, d2[mt], 0, 0, 0);
            }
        }

        // ---- LayerNorm(112) + delta + Z update (+ projection) ----
        float s = 0.f;
        #pragma unroll
        for (int mt = 0; mt < 7; ++mt) s += d2[mt][0] + d2[mt][1] + d2[mt][2] + d2[mt][3];
        s += __shfl_xor(s, 16); s += __shfl_xor(s, 32);
        float m = s * (1.f/EH);
        float q = 0.f;
        #pragma unroll
        for (int mt = 0; mt < 7; ++mt) {
            #pragma unroll
            for (int r = 0; r < 4; ++r) { float dd = d2[mt][r] - m; q = fmaf(dd, dd, q); }
        }
        q += __shfl_xor(q, 16); q += __shfl_xor(q, 32);
        float inv = rsqrtf(q*(1.f/EH) + 1e-6f);

        float S1[4] = {0,0,0,0};
        #pragma unroll
        for (int mt = 0; mt < 7; ++mt) {
            #pragma unroll
            for (int r = 0; r < 4; ++r) S1[r] = fmaf(d2[mt][r], gz[mt][r], S1[r]);
        }
        f32x4 zn;
        #pragma unroll
        for (int r = 0; r < 4; ++r)
            zn[r] = zv[r] + (fmaf(-m, Gz[r], S1[r]) * inv + Bz[r]);

        if (!LAST) {
            *reinterpret_cast<f32x4*>(Z + (row0 + i)*Ee + 4*g) = zn;
        } else {
            float o0 = zn[0]*wpa[0] + zn[1]*wpa[1] + zn[2]*wpa[2] + zn[3]*wpa[3];
            float o1 = zn[0]*wpb[0] + zn[1]*wpb[1] + zn[2]*wpb[2] + zn[3]*wpb[3];
            o0 += __shfl_xor(o0, 16); o0 += __shfl_xor(o0, 32);
            o1 += __shfl_xor(o1, 16); o1 += __shfl_xor(o1, 32);
            if (g == 0) {
                float2 o; o.x = o0 + bp0; o.y = o1 + bp1;
                *reinterpret_cast<float2*>(out + (row0 + i)*2) = o;
            }
        }
    }
}

// ---------------------------------------------------------------- launcher --
extern "C" void kernel_launch(void* const* d_in, const int* in_sizes, int n_in,
                              void* d_out, int out_size, void* d_ws, size_t ws_size,
                              hipStream_t stream)
{
    const float* X      = (const float*)d_in[0];
    const int*   avail  = (const int*)  d_in[1];
    const float* W_enc1 = (const float*)d_in[2];  const float* b_enc1 = (const float*)d_in[3];
    const float* W_enc2 = (const float*)d_in[4];  const float* b_enc2 = (const float*)d_in[5];
    const float* W_enc3 = (const float*)d_in[6];  const float* b_enc3 = (const float*)d_in[7];
    const float* g_enc  = (const float*)d_in[8];  const float* be_enc = (const float*)d_in[9];
    const float* W_agg  = (const float*)d_in[10]; const float* b_agg  = (const float*)d_in[11];
    const float* W_phi1 = (const float*)d_in[12]; const float* b_phi1 = (const float*)d_in[13];
    const float* W_phi2 = (const float*)d_in[14]; const float* b_phi2 = (const float*)d_in[15];
    const float* g_phi  = (const float*)d_in[16]; const float* be_phi = (const float*)d_in[17];
    const float* W_proj = (const float*)d_in[18]; const float* b_proj = (const float*)d_in[19];
    float* out = (float*)d_out;

    unsigned short* XeBF = (unsigned short*)d_ws;             // bf16 [NROW][16], 16 MB
    float* Z  = (float*)((char*)d_ws + (size_t)NROW*Ee*2);    // f32  [NROW][16], 32 MB
    float* Zb = Z + (size_t)NROW*Ee;                          // [128][7]

    enc_kernel<<<NROW/256, 256, 0, stream>>>(
        X, W_enc1, b_enc1, W_enc2, b_enc2, W_enc3, b_enc3, g_enc, be_enc, XeBF, Z);

    for (int d = 0; d < 3; ++d) {
        zbar_kernel<<<Bb, 512, 0, stream>>>(
            Z, avail, W_agg + d*Ee*Hh, b_agg + d*Hh, Zb);
        if (d < 2) {
            phi_mfma<false><<<NBLK, 256, 0, stream>>>(
                XeBF, Z, Zb,
                W_phi1 + d*Ee*EH, b_phi1 + d*EH,
                W_phi2 + d*EH*EH, b_phi2 + d*EH,
                g_phi + d*EH, be_phi + d*EH, W_proj, b_proj, out);
        } else {
            phi_mfma<true><<<NBLK, 256, 0, stream>>>(
                XeBF, Z, Zb,
                W_phi1 + d*Ee*EH, b_phi1 + d*EH,
                W_phi2 + d*EH*EH, b_phi2 + d*EH,
                g_phi + d*EH, be_phi + d*EH, W_proj, b_proj, out);
        }
    }
}

// Round 3
// 209.069 us; speedup vs baseline: 7.2538x; 2.5059x over previous
//
#include <hip/hip_runtime.h>
#include <hip/hip_bf16.h>

#define Bb 128
#define Nn 4096
#define Ff 32
#define Ee 16
#define Hh 7
#define EH 112
#define NROW (Bb*Nn)
#define PS 136              // ushort stride of per-wave phi1 LDS row (272 B, 16B-aligned)
#define TPB_TILES 16        // 16-row tiles per block
#define NBLK (NROW/16/TPB_TILES)   // 2048 blocks

typedef __attribute__((ext_vector_type(8))) short  bf16x8;
typedef __attribute__((ext_vector_type(4))) float  f32x4;
typedef __attribute__((ext_vector_type(4))) unsigned int u32x4;
typedef __attribute__((ext_vector_type(2))) unsigned int u32x2;

__device__ inline unsigned pack2(float a, float b) {
    __hip_bfloat162 h = __float22bfloat162_rn(make_float2(a, b));
    return *reinterpret_cast<unsigned*>(&h);
}
union BF8 { unsigned u[4]; bf16x8 v; u32x4 q; };

// ---------------------------------------------------------------- encoder ---
__global__ __launch_bounds__(256) void enc_kernel(
    const float* __restrict__ X,
    const float* __restrict__ W1, const float* __restrict__ b1,
    const float* __restrict__ W2, const float* __restrict__ b2,
    const float* __restrict__ W3, const float* __restrict__ b3,
    const float* __restrict__ g,  const float* __restrict__ be,
    unsigned short* __restrict__ XeBF, float* __restrict__ Z)
{
    __shared__ float sW1[Ff*Ee], sW2[Ee*Ee], sW3[Ee*Ee];
    __shared__ float sb1[Ee], sb2[Ee], sb3[Ee], sg[Ee], sbe[Ee];
    int tid = threadIdx.x;
    for (int i = tid; i < Ff*Ee; i += 256) sW1[i] = W1[i];
    for (int i = tid; i < Ee*Ee; i += 256) { sW2[i] = W2[i]; sW3[i] = W3[i]; }
    if (tid < Ee) { sb1[tid]=b1[tid]; sb2[tid]=b2[tid]; sb3[tid]=b3[tid];
                    sg[tid]=g[tid];   sbe[tid]=be[tid]; }
    __syncthreads();

    size_t row = (size_t)blockIdx.x * 256u + (unsigned)tid;
    const float4* xr = reinterpret_cast<const float4*>(X + row * Ff);
    float x[Ff];
    #pragma unroll
    for (int i = 0; i < Ff/4; ++i) {
        float4 v = xr[i];
        x[4*i+0]=v.x; x[4*i+1]=v.y; x[4*i+2]=v.z; x[4*i+3]=v.w;
    }
    float h1[Ee];
    #pragma unroll
    for (int e = 0; e < Ee; ++e) h1[e] = sb1[e];
    #pragma unroll 4
    for (int k = 0; k < Ff; ++k) {
        float xk = x[k];
        #pragma unroll
        for (int e = 0; e < Ee; ++e) h1[e] = fmaf(xk, sW1[k*Ee+e], h1[e]);
    }
    #pragma unroll
    for (int e = 0; e < Ee; ++e) h1[e] = fmaxf(h1[e], 0.f);

    float h2[Ee];
    #pragma unroll
    for (int e = 0; e < Ee; ++e) h2[e] = sb2[e];
    #pragma unroll 4
    for (int k = 0; k < Ee; ++k) {
        float hk = h1[k];
        #pragma unroll
        for (int e = 0; e < Ee; ++e) h2[e] = fmaf(hk, sW2[k*Ee+e], h2[e]);
    }
    #pragma unroll
    for (int e = 0; e < Ee; ++e) h2[e] = fmaxf(h2[e], 0.f);

    float z[Ee];
    #pragma unroll
    for (int e = 0; e < Ee; ++e) z[e] = sb3[e];
    #pragma unroll 4
    for (int k = 0; k < Ee; ++k) {
        float hk = h2[k];
        #pragma unroll
        for (int e = 0; e < Ee; ++e) z[e] = fmaf(hk, sW3[k*Ee+e], z[e]);
    }
    float m = 0.f;
    #pragma unroll
    for (int e = 0; e < Ee; ++e) m += z[e];
    m *= (1.f/Ee);
    float v = 0.f;
    #pragma unroll
    for (int e = 0; e < Ee; ++e) { float d = z[e]-m; v += d*d; }
    v *= (1.f/Ee);
    float inv = rsqrtf(v + 1e-6f);
    #pragma unroll
    for (int e = 0; e < Ee; ++e) z[e] = (z[e]-m)*inv*sg[e] + sbe[e];

    float4* zo = reinterpret_cast<float4*>(Z + row*Ee);
    #pragma unroll
    for (int i = 0; i < Ee/4; ++i) {
        float4 o; o.x=z[4*i]; o.y=z[4*i+1]; o.z=z[4*i+2]; o.w=z[4*i+3];
        zo[i] = o;
    }
    unsigned us[8];
    #pragma unroll
    for (int j = 0; j < 8; ++j) us[j] = pack2(z[2*j], z[2*j+1]);
    u32x4 lo = {us[0],us[1],us[2],us[3]};
    u32x4 hi = {us[4],us[5],us[6],us[7]};
    u32x4* xo = reinterpret_cast<u32x4*>(XeBF + row*Ee);
    xo[0] = lo; xo[1] = hi;
}

// -------------------------------------------------- weight fragment packer --
__global__ __launch_bounds__(256) void wpack(
    const float* __restrict__ W_phi2, const float* __restrict__ W_phi1,
    unsigned short* __restrict__ W2F, unsigned short* __restrict__ W1F)
{
    int idx = blockIdx.x*256 + threadIdx.x;
    if (idx < 3*28*64) {
        int d = idx / (28*64); int r = idx % (28*64);
        int f = r >> 6, l = r & 63;
        int lg = l >> 4, li = l & 15, mt = f >> 2, kt = f & 3;
        const float* W2g = W_phi2 + (size_t)d*EH*EH;
        unsigned v[4];
        #pragma unroll
        for (int jj = 0; jj < 4; ++jj) {
            int k0 = kt*32 + lg*8 + jj*2;
            float a = (k0   < EH) ? W2g[(size_t)k0*EH     + mt*16 + li] : 0.f;
            float c = (k0+1 < EH) ? W2g[(size_t)(k0+1)*EH + mt*16 + li] : 0.f;
            v[jj] = pack2(a, c);
        }
        u32x4 q = {v[0], v[1], v[2], v[3]};
        *reinterpret_cast<u32x4*>(W2F + (size_t)idx*8) = q;
    } else if (idx < 3*28*64 + 3*7*64) {
        int r2 = idx - 3*28*64;
        int d = r2 / (7*64); int r = r2 % (7*64);
        int mt = r >> 6, l = r & 63;
        int g = l >> 4, i = l & 15;
        const float* W1g = W_phi1 + (size_t)d*Ee*EH;
        unsigned v[4];
        #pragma unroll
        for (int jj = 0; jj < 4; ++jj) {
            float a = 0.f, c = 0.f;
            if (g < 2) {
                a = W1g[(size_t)(g*8 + jj*2)  *EH + mt*16 + i];
                c = W1g[(size_t)(g*8 + jj*2+1)*EH + mt*16 + i];
            }
            v[jj] = pack2(a, c);
        }
        u32x4 q = {v[0], v[1], v[2], v[3]};
        *reinterpret_cast<u32x4*>(W1F + (size_t)r2*8) = q;
    }
}

// ----------------------------------------------------------- Zbar partials --
__global__ __launch_bounds__(256) void zbar_part(
    const float* __restrict__ Z, const int* __restrict__ avail,
    const float* __restrict__ Wagg, const float* __restrict__ bagg,
    float* __restrict__ part)
{
    __shared__ float sW[Ee*Hh];
    __shared__ float sb[Hh];
    __shared__ float red[256][8];
    int b = blockIdx.x >> 3, p = blockIdx.x & 7;
    int tid = threadIdx.x;
    if (tid < Ee*Hh) sW[tid] = Wagg[tid];
    if (tid < Hh)    sb[tid] = bagg[tid];
    __syncthreads();

    float acc[Hh]; float cnt = 0.f;
    #pragma unroll
    for (int h = 0; h < Hh; ++h) acc[h] = 0.f;

    #pragma unroll
    for (int it = 0; it < 2; ++it) {
        int n = p*512 + it*256 + tid;
        size_t row = (size_t)b*Nn + n;
        const float4* zr = reinterpret_cast<const float4*>(Z + row*Ee);
        float zs[Ee];
        #pragma unroll
        for (int i = 0; i < Ee/4; ++i) {
            float4 v = zr[i];
            zs[4*i+0]=v.x*v.x; zs[4*i+1]=v.y*v.y; zs[4*i+2]=v.z*v.z; zs[4*i+3]=v.w*v.w;
        }
        float fc[Hh];
        #pragma unroll
        for (int h = 0; h < Hh; ++h) fc[h] = sb[h];
        #pragma unroll 4
        for (int e = 0; e < Ee; ++e) {
            float ze = zs[e];
            #pragma unroll
            for (int h = 0; h < Hh; ++h) fc[h] = fmaf(ze, sW[e*Hh+h], fc[h]);
        }
        float af = (float)avail[(size_t)b*Nn + n];
        #pragma unroll
        for (int h = 0; h < Hh; ++h) acc[h] = fmaf(af, fc[h], acc[h]);
        cnt += af;
    }
    #pragma unroll
    for (int h = 0; h < Hh; ++h) red[tid][h] = acc[h];
    red[tid][7] = cnt;
    __syncthreads();
    for (int s = 128; s > 0; s >>= 1) {
        if (tid < s) {
            #pragma unroll
            for (int i = 0; i < 8; ++i) red[tid][i] += red[tid+s][i];
        }
        __syncthreads();
    }
    if (tid < 8) part[((size_t)b*8 + p)*8 + tid] = red[0][tid];
}

__global__ __launch_bounds__(1024) void zbar_fin(
    const float* __restrict__ part, float* __restrict__ Zbar)
{
    int tid = threadIdx.x;          // 1024 = 128 batches x 8 slots
    int b = tid >> 3, h = tid & 7;
    float s = 0.f;
    #pragma unroll
    for (int p = 0; p < 8; ++p) s += part[((size_t)b*8 + p)*8 + h];
    float cnt = __shfl(s, (tid & 63) | 7);
    if (h < Hh) Zbar[b*Hh + h] = s / fmaxf(cnt, 1.f);
}

// ---------------------------------------------------- phi via MFMA (+proj) --
template<bool LAST>
__global__ __launch_bounds__(256, 3) void phi_mfma(
    const unsigned short* __restrict__ Xe,   // bf16 [NROW][16]
    float* __restrict__ Z,
    const float* __restrict__ Zbar,
    const unsigned short* __restrict__ W1F,  // packed A-frags [7][64][8]
    const unsigned short* __restrict__ W2F,  // packed A-frags [28][64][8]
    const float* __restrict__ b1g, const float* __restrict__ b2g,
    const float* __restrict__ gg,  const float* __restrict__ beg,
    const float* __restrict__ Wp,  const float* __restrict__ bp,
    float* __restrict__ out)
{
    __shared__ __align__(16) unsigned short sW2F[28*512];
    __shared__ __align__(16) unsigned short sP1[4][16*PS];
    __shared__ __align__(16) float sB1[EH], sB2[EH];

    int tid  = threadIdx.x;
    int wave = tid >> 6, lane = tid & 63;
    int g = lane >> 4, i = lane & 15;

    // coalesced stage of pre-packed W2 fragments
    for (int p = tid; p < 28*64; p += 256)
        *reinterpret_cast<u32x4*>(&sW2F[p*8]) =
            *reinterpret_cast<const u32x4*>(W2F + (size_t)p*8);
    // zero sP1 (covers the k=112..127 pad forever)
    for (int p = tid; p < (4*16*PS)/8; p += 256) {
        u32x4 zq = {0u,0u,0u,0u};
        reinterpret_cast<u32x4*>(&sP1[0][0])[p] = zq;
    }
    if (tid < EH) { sB1[tid] = b1g[tid]; sB2[tid] = b2g[tid]; }

    // W1 A-fragments: 7 coalesced b128 loads
    bf16x8 aW1[7];
    #pragma unroll
    for (int mt = 0; mt < 7; ++mt)
        aW1[mt] = *reinterpret_cast<const bf16x8*>(W1F + (size_t)(mt*64 + lane)*8);

    // per-batch constants
    int b = blockIdx.x / (Nn/(TPB_TILES*16));    // 16 blocks per batch
    f32x4 gz[7];
    float Gz[4] = {0,0,0,0}, Bz[4] = {0,0,0,0};
    #pragma unroll
    for (int mt = 0; mt < 7; ++mt) {
        float zbm = Zbar[b*Hh + mt] * (1.f/Hh);
        f32x4 pg = *reinterpret_cast<const f32x4*>(gg  + mt*16 + 4*g);
        f32x4 pe = *reinterpret_cast<const f32x4*>(beg + mt*16 + 4*g);
        #pragma unroll
        for (int r = 0; r < 4; ++r) {
            float gzv = pg[r] * zbm;
            gz[mt][r] = gzv;
            Gz[r] += gzv;
            Bz[r] += pe[r] * zbm;
        }
    }
    float wpa[4] = {0,0,0,0}, wpb[4] = {0,0,0,0}, bp0 = 0.f, bp1 = 0.f;
    if (LAST) {
        f32x4 u0 = *reinterpret_cast<const f32x4*>(Wp + 8*g);
        f32x4 u1 = *reinterpret_cast<const f32x4*>(Wp + 8*g + 4);
        wpa[0]=u0[0]; wpa[1]=u0[2]; wpa[2]=u1[0]; wpa[3]=u1[2];
        wpb[0]=u0[1]; wpb[1]=u0[3]; wpb[2]=u1[1]; wpb[3]=u1[3];
        bp0 = bp[0]; bp1 = bp[1];
    }
    __syncthreads();

    unsigned short* myP1 = &sP1[wave][0];
    size_t r0 = (size_t)(blockIdx.x*TPB_TILES + wave*4) * 16;

    // ---- prefetch ALL 4 tiles' global inputs up-front ----
    BF8 zzu; zzu.u[0]=zzu.u[1]=zzu.u[2]=zzu.u[3]=0u;
    bf16x8 bx0 = zzu.v, bx1 = zzu.v, bx2 = zzu.v, bx3 = zzu.v;
    if (g < 2) {
        const unsigned short* xp = Xe + (r0 + i)*Ee + g*8;
        bx0 = *reinterpret_cast<const bf16x8*>(xp);
        bx1 = *reinterpret_cast<const bf16x8*>(xp + 16*Ee);
        bx2 = *reinterpret_cast<const bf16x8*>(xp + 32*Ee);
        bx3 = *reinterpret_cast<const bf16x8*>(xp + 48*Ee);
    }
    const float* zp = Z + (r0 + i)*Ee + 4*g;
    f32x4 zv0 = *reinterpret_cast<const f32x4*>(zp);
    f32x4 zv1 = *reinterpret_cast<const f32x4*>(zp + 16*Ee);
    f32x4 zv2 = *reinterpret_cast<const f32x4*>(zp + 32*Ee);
    f32x4 zv3 = *reinterpret_cast<const f32x4*>(zp + 48*Ee);

    auto tileop = [&](bf16x8 bx, f32x4 zv, size_t row0) {
        // ---- phi1^T = W1^T @ Xe^T (7 MFMAs), relu, pack, stash in LDS ----
        #pragma unroll
        for (int mt = 0; mt < 7; ++mt) {
            f32x4 c = *reinterpret_cast<const f32x4*>(&sB1[mt*16 + 4*g]);
            f32x4 d = __builtin_amdgcn_mfma_f32_16x16x32_bf16(aW1[mt], bx, c, 0, 0, 0);
            #pragma unroll
            for (int r = 0; r < 4; ++r) d[r] = fmaxf(d[r], 0.f);
            u32x2 w = {pack2(d[0], d[1]), pack2(d[2], d[3])};
            *reinterpret_cast<u32x2*>(&myP1[i*PS + mt*16 + 4*g]) = w;
        }
        // ---- phi2^T = W2^T @ phi1^T (28 MFMAs) ----
        f32x4 d2[7];
        #pragma unroll
        for (int mt = 0; mt < 7; ++mt)
            d2[mt] = *reinterpret_cast<const f32x4*>(&sB2[mt*16 + 4*g]);
        #pragma unroll
        for (int kt = 0; kt < 4; ++kt) {
            bf16x8 bpv = *reinterpret_cast<const bf16x8*>(&myP1[i*PS + kt*32 + 8*g]);
            #pragma unroll
            for (int mt = 0; mt < 7; ++mt) {
                bf16x8 a = *reinterpret_cast<const bf16x8*>(&sW2F[(mt*4 + kt)*512 + lane*8]);
                d2[mt] = __builtin_amdgcn_mfma_f32_16x16x32_bf16(a, bpv, d2[mt], 0, 0, 0);
            }
        }
        // ---- LayerNorm(112) + delta + Z update (+ projection) ----
        float s = 0.f;
        #pragma unroll
        for (int mt = 0; mt < 7; ++mt) s += d2[mt][0] + d2[mt][1] + d2[mt][2] + d2[mt][3];
        s += __shfl_xor(s, 16); s += __shfl_xor(s, 32);
        float m = s * (1.f/EH);
        float q = 0.f;
        #pragma unroll
        for (int mt = 0; mt < 7; ++mt) {
            #pragma unroll
            for (int r = 0; r < 4; ++r) { float dd = d2[mt][r] - m; q = fmaf(dd, dd, q); }
        }
        q += __shfl_xor(q, 16); q += __shfl_xor(q, 32);
        float inv = rsqrtf(q*(1.f/EH) + 1e-6f);

        float S1[4] = {0,0,0,0};
        #pragma unroll
        for (int mt = 0; mt < 7; ++mt) {
            #pragma unroll
            for (int r = 0; r < 4; ++r) S1[r] = fmaf(d2[mt][r], gz[mt][r], S1[r]);
        }
        f32x4 zn;
        #pragma unroll
        for (int r = 0; r < 4; ++r)
            zn[r] = zv[r] + (fmaf(-m, Gz[r], S1[r]) * inv + Bz[r]);

        if (!LAST) {
            *reinterpret_cast<f32x4*>(Z + (row0 + i)*Ee + 4*g) = zn;
        } else {
            float o0 = zn[0]*wpa[0] + zn[1]*wpa[1] + zn[2]*wpa[2] + zn[3]*wpa[3];
            float o1 = zn[0]*wpb[0] + zn[1]*wpb[1] + zn[2]*wpb[2] + zn[3]*wpb[3];
            o0 += __shfl_xor(o0, 16); o0 += __shfl_xor(o0, 32);
            o1 += __shfl_xor(o1, 16); o1 += __shfl_xor(o1, 32);
            if (g == 0) {
                float2 o; o.x = o0 + bp0; o.y = o1 + bp1;
                *reinterpret_cast<float2*>(out + (row0 + i)*2) = o;
            }
        }
    };

    tileop(bx0, zv0, r0);
    tileop(bx1, zv1, r0 + 16);
    tileop(bx2, zv2, r0 + 32);
    tileop(bx3, zv3, r0 + 48);
}

// ---------------------------------------------------------------- launcher --
extern "C" void kernel_launch(void* const* d_in, const int* in_sizes, int n_in,
                              void* d_out, int out_size, void* d_ws, size_t ws_size,
                              hipStream_t stream)
{
    const float* X      = (const float*)d_in[0];
    const int*   avail  = (const int*)  d_in[1];
    const float* W_enc1 = (const float*)d_in[2];  const float* b_enc1 = (const float*)d_in[3];
    const float* W_enc2 = (const float*)d_in[4];  const float* b_enc2 = (const float*)d_in[5];
    const float* W_enc3 = (const float*)d_in[6];  const float* b_enc3 = (const float*)d_in[7];
    const float* g_enc  = (const float*)d_in[8];  const float* be_enc = (const float*)d_in[9];
    const float* W_agg  = (const float*)d_in[10]; const float* b_agg  = (const float*)d_in[11];
    const float* W_phi1 = (const float*)d_in[12]; const float* b_phi1 = (const float*)d_in[13];
    const float* W_phi2 = (const float*)d_in[14]; const float* b_phi2 = (const float*)d_in[15];
    const float* g_phi  = (const float*)d_in[16]; const float* be_phi = (const float*)d_in[17];
    const float* W_proj = (const float*)d_in[18]; const float* b_proj = (const float*)d_in[19];
    float* out = (float*)d_out;

    char* ws = (char*)d_ws;
    unsigned short* XeBF = (unsigned short*)ws;                    // 16 MB
    float* Z   = (float*)(ws + (size_t)NROW*Ee*2);                 // 32 MB
    char*  p   = ws + (size_t)NROW*Ee*2 + (size_t)NROW*Ee*4;
    float* Zb  = (float*)p;                 p += 4096;             // [128][7]
    float* part= (float*)p;                 p += (size_t)Bb*8*8*4; // [128][8][8]
    unsigned short* W2F = (unsigned short*)p; p += (size_t)3*28*512*2;
    unsigned short* W1F = (unsigned short*)p;

    wpack<<<(3*28*64 + 3*7*64 + 255)/256, 256, 0, stream>>>(W_phi2, W_phi1, W2F, W1F);

    enc_kernel<<<NROW/256, 256, 0, stream>>>(
        X, W_enc1, b_enc1, W_enc2, b_enc2, W_enc3, b_enc3, g_enc, be_enc, XeBF, Z);

    for (int d = 0; d < 3; ++d) {
        zbar_part<<<Bb*8, 256, 0, stream>>>(
            Z, avail, W_agg + d*Ee*Hh, b_agg + d*Hh, part);
        zbar_fin<<<1, 1024, 0, stream>>>(part, Zb);
        if (d < 2) {
            phi_mfma<false><<<NBLK, 256, 0, stream>>>(
                XeBF, Z, Zb,
                W1F + (size_t)d*7*512, W2F + (size_t)d*28*512,
                b_phi1 + d*EH, b_phi2 + d*EH,
                g_phi + d*EH, be_phi + d*EH, W_proj, b_proj, out);
        } else {
            phi_mfma<true><<<NBLK, 256, 0, stream>>>(
                XeBF, Z, Zb,
                W1F + (size_t)d*7*512, W2F + (size_t)d*28*512,
                b_phi1 + d*EH, b_phi2 + d*EH,
                g_phi + d*EH, be_phi + d*EH, W_proj, b_proj, out);
        }
    }
}

// Round 4
// 167.867 us; speedup vs baseline: 9.0342x; 1.2454x over previous
//
#include <hip/hip_runtime.h>
#include <hip/hip_bf16.h>

#define Bb 128
#define Nn 4096
#define Ff 32
#define Ee 16
#define Hh 7
#define EH 112
#define NROW (Bb*Nn)
#define PS 136              // ushort stride of phi1 LDS row (272 B, 16B-aligned)
#define NBLK 2048           // phi/enc blocks: 256 rows each

typedef __attribute__((ext_vector_type(8))) short  bf16x8;
typedef __attribute__((ext_vector_type(4))) float  f32x4;
typedef __attribute__((ext_vector_type(4))) unsigned int u32x4;
typedef __attribute__((ext_vector_type(2))) unsigned int u32x2;

__device__ inline unsigned pack2(float a, float b) {
    __hip_bfloat162 h = __float22bfloat162_rn(make_float2(a, b));
    return *reinterpret_cast<unsigned*>(&h);
}
union BF8 { unsigned u[4]; bf16x8 v; u32x4 q; };

// ---------------------------------------------------------------- encoder ---
// Writes X_embd (bf16) only; Z_0 == X_embd. Also accumulates zbar_0 partials.
__global__ __launch_bounds__(256) void enc_kernel(
    const float* __restrict__ X,
    const float* __restrict__ W1, const float* __restrict__ b1,
    const float* __restrict__ W2, const float* __restrict__ b2,
    const float* __restrict__ W3, const float* __restrict__ b3,
    const float* __restrict__ g,  const float* __restrict__ be,
    const float* __restrict__ Wagg0, const int* __restrict__ avail,
    unsigned short* __restrict__ XeBF, float* __restrict__ acc0)
{
    __shared__ float sW1[Ff*Ee], sW2[Ee*Ee], sW3[Ee*Ee];
    __shared__ float sb1[Ee], sb2[Ee], sb3[Ee], sg[Ee], sbe[Ee];
    __shared__ float sWq[Ee*Hh];
    __shared__ float red[256][8];
    int tid = threadIdx.x;
    for (int i = tid; i < Ff*Ee; i += 256) sW1[i] = W1[i];
    for (int i = tid; i < Ee*Ee; i += 256) { sW2[i] = W2[i]; sW3[i] = W3[i]; }
    if (tid < Ee) { sb1[tid]=b1[tid]; sb2[tid]=b2[tid]; sb3[tid]=b3[tid];
                    sg[tid]=g[tid];   sbe[tid]=be[tid]; }
    if (tid < Ee*Hh) sWq[tid] = Wagg0[tid];
    __syncthreads();

    size_t row = (size_t)blockIdx.x * 256u + (unsigned)tid;
    const float4* xr = reinterpret_cast<const float4*>(X + row * Ff);
    float x[Ff];
    #pragma unroll
    for (int i = 0; i < Ff/4; ++i) {
        float4 v = xr[i];
        x[4*i+0]=v.x; x[4*i+1]=v.y; x[4*i+2]=v.z; x[4*i+3]=v.w;
    }
    float h1[Ee];
    #pragma unroll
    for (int e = 0; e < Ee; ++e) h1[e] = sb1[e];
    #pragma unroll 4
    for (int k = 0; k < Ff; ++k) {
        float xk = x[k];
        #pragma unroll
        for (int e = 0; e < Ee; ++e) h1[e] = fmaf(xk, sW1[k*Ee+e], h1[e]);
    }
    #pragma unroll
    for (int e = 0; e < Ee; ++e) h1[e] = fmaxf(h1[e], 0.f);

    float h2[Ee];
    #pragma unroll
    for (int e = 0; e < Ee; ++e) h2[e] = sb2[e];
    #pragma unroll 4
    for (int k = 0; k < Ee; ++k) {
        float hk = h1[k];
        #pragma unroll
        for (int e = 0; e < Ee; ++e) h2[e] = fmaf(hk, sW2[k*Ee+e], h2[e]);
    }
    #pragma unroll
    for (int e = 0; e < Ee; ++e) h2[e] = fmaxf(h2[e], 0.f);

    float z[Ee];
    #pragma unroll
    for (int e = 0; e < Ee; ++e) z[e] = sb3[e];
    #pragma unroll 4
    for (int k = 0; k < Ee; ++k) {
        float hk = h2[k];
        #pragma unroll
        for (int e = 0; e < Ee; ++e) z[e] = fmaf(hk, sW3[k*Ee+e], z[e]);
    }
    float m = 0.f;
    #pragma unroll
    for (int e = 0; e < Ee; ++e) m += z[e];
    m *= (1.f/Ee);
    float v = 0.f;
    #pragma unroll
    for (int e = 0; e < Ee; ++e) { float d = z[e]-m; v += d*d; }
    v *= (1.f/Ee);
    float inv = rsqrtf(v + 1e-6f);
    #pragma unroll
    for (int e = 0; e < Ee; ++e) z[e] = (z[e]-m)*inv*sg[e] + sbe[e];

    // X_embd (== Z_0) in bf16
    unsigned us[8];
    #pragma unroll
    for (int j = 0; j < 8; ++j) us[j] = pack2(z[2*j], z[2*j+1]);
    u32x4 lo = {us[0],us[1],us[2],us[3]};
    u32x4 hi = {us[4],us[5],us[6],us[7]};
    u32x4* xo = reinterpret_cast<u32x4*>(XeBF + row*Ee);
    xo[0] = lo; xo[1] = hi;

    // ---- zbar_0 partials: fc = z^2 @ Wagg0, masked ----
    float af = (float)avail[row];
    float fc[Hh];
    #pragma unroll
    for (int h = 0; h < Hh; ++h) fc[h] = 0.f;
    #pragma unroll
    for (int e = 0; e < Ee; ++e) {
        float z2 = z[e]*z[e];
        #pragma unroll
        for (int h = 0; h < Hh; ++h) fc[h] = fmaf(z2, sWq[e*Hh+h], fc[h]);
    }
    #pragma unroll
    for (int h = 0; h < Hh; ++h) red[tid][h] = af * fc[h];
    red[tid][7] = af;
    __syncthreads();
    for (int s = 128; s > 0; s >>= 1) {
        if (tid < s) {
            #pragma unroll
            for (int q2 = 0; q2 < 8; ++q2) red[tid][q2] += red[tid+s][q2];
        }
        __syncthreads();
    }
    if (tid < 8) atomicAdd(&acc0[(blockIdx.x >> 4)*8 + tid], red[0][tid]);
}

// -------------------------------------------------- weight fragment packer --
// Biases folded into the K-pad: W1F k=16 row = b1; W2F k=112 row = b2.
__global__ __launch_bounds__(256) void wpack(
    const float* __restrict__ W_phi2, const float* __restrict__ W_phi1,
    const float* __restrict__ b_phi1, const float* __restrict__ b_phi2,
    unsigned short* __restrict__ W2F, unsigned short* __restrict__ W1F)
{
    int idx = blockIdx.x*256 + threadIdx.x;
    if (idx < 3*28*64) {
        int d = idx / (28*64); int r = idx % (28*64);
        int f = r >> 6, l = r & 63;
        int lg = l >> 4, li = l & 15, mt = f >> 2, kt = f & 3;
        const float* W2g = W_phi2 + (size_t)d*EH*EH;
        const float* b2g = b_phi2 + (size_t)d*EH;
        int mm = mt*16 + li;
        unsigned v[4];
        #pragma unroll
        for (int jj = 0; jj < 4; ++jj) {
            int k0 = kt*32 + lg*8 + jj*2;
            float a = (k0 < EH) ? W2g[(size_t)k0*EH + mm]
                                : (k0 == EH ? b2g[mm] : 0.f);
            float c = (k0+1 < EH) ? W2g[(size_t)(k0+1)*EH + mm] : 0.f;
            v[jj] = pack2(a, c);
        }
        u32x4 q = {v[0], v[1], v[2], v[3]};
        *reinterpret_cast<u32x4*>(W2F + (size_t)idx*8) = q;
    } else if (idx < 3*28*64 + 3*7*64) {
        int r2 = idx - 3*28*64;
        int d = r2 / (7*64); int r = r2 % (7*64);
        int mt = r >> 6, l = r & 63;
        int g = l >> 4, i = l & 15;
        const float* W1g = W_phi1 + (size_t)d*Ee*EH;
        const float* b1g = b_phi1 + (size_t)d*EH;
        int mm = mt*16 + i;
        unsigned v[4];
        #pragma unroll
        for (int jj = 0; jj < 4; ++jj) {
            float a = 0.f, c = 0.f;
            if (g < 2) {
                a = W1g[(size_t)(g*8 + jj*2)  *EH + mm];
                c = W1g[(size_t)(g*8 + jj*2+1)*EH + mm];
            } else if (g == 2 && jj == 0) {
                a = b1g[mm];                    // k=16 bias row
            }
            v[jj] = pack2(a, c);
        }
        u32x4 q = {v[0], v[1], v[2], v[3]};
        *reinterpret_cast<u32x4*>(W1F + (size_t)r2*8) = q;
    }
}

// ------------------------------------- phi via MFMA + fused zbar (+proj) ----
template<bool LAST>
__global__ __launch_bounds__(256, 2) void phi_mfma(
    const unsigned short* __restrict__ Zin,   // bf16 [NROW][16]
    const unsigned short* __restrict__ Xe,    // bf16 [NROW][16]
    unsigned short* __restrict__ Zout,
    const float* __restrict__ accIn, const float* __restrict__ baggD,
    const float* __restrict__ WaggN, float* __restrict__ accN,
    const int* __restrict__ avail,
    const unsigned short* __restrict__ W1F,   // packed A-frags [7][64][8]
    const unsigned short* __restrict__ W2F,   // packed A-frags [28][64][8]
    const float* __restrict__ gg,  const float* __restrict__ beg,
    const float* __restrict__ Wp,  const float* __restrict__ bp,
    float* __restrict__ out)
{
    __shared__ __align__(16) unsigned short sW2F[28*512];
    __shared__ __align__(16) unsigned short sP1[4][2][16*PS];
    __shared__ float sRed[4][8];

    int tid  = threadIdx.x;
    int wave = tid >> 6, lane = tid & 63;
    int g = lane >> 4, i = lane & 15;

    for (int p = tid; p < 28*64; p += 256)
        *reinterpret_cast<u32x4*>(&sW2F[p*8]) =
            *reinterpret_cast<const u32x4*>(W2F + (size_t)p*8);
    for (int p = tid; p < (4*2*16*PS)/8; p += 256) {
        u32x4 zq = {0u,0u,0u,0u};
        reinterpret_cast<u32x4*>(&sP1[0][0][0])[p] = zq;
    }
    __syncthreads();
    if (tid < 128) {          // ones column at k=112 (phi2 bias row multiplier)
        int w = tid >> 5, bb = (tid >> 4) & 1, r = tid & 15;
        sP1[w][bb][r*PS + 112] = 0x3F80;
    }

    int b = blockIdx.x >> 4;                     // 16 blocks per batch
    float cntb = accIn[b*8 + 7];
    float cden = fmaxf(cntb, 1.f);
    float zb[Hh];
    #pragma unroll
    for (int h = 0; h < Hh; ++h)
        zb[h] = (accIn[b*8 + h] + baggD[h]*cntb) / cden * (1.f/Hh);

    f32x4 gz[7];
    float Gz[4] = {0,0,0,0}, Bz[4] = {0,0,0,0};
    #pragma unroll
    for (int mt = 0; mt < 7; ++mt) {
        f32x4 pg = *reinterpret_cast<const f32x4*>(gg  + mt*16 + 4*g);
        f32x4 pe = *reinterpret_cast<const f32x4*>(beg + mt*16 + 4*g);
        #pragma unroll
        for (int r = 0; r < 4; ++r) {
            float gzv = pg[r] * zb[mt];
            gz[mt][r] = gzv;
            Gz[r] += gzv;
            Bz[r] += pe[r] * zb[mt];
        }
    }
    bf16x8 aW1[7];
    #pragma unroll
    for (int mt = 0; mt < 7; ++mt)
        aW1[mt] = *reinterpret_cast<const bf16x8*>(W1F + (size_t)(mt*64 + lane)*8);

    f32x4 wq[7];                 // Wagg_next[(4g+r)][h]
    if (!LAST) {
        #pragma unroll
        for (int h = 0; h < Hh; ++h)
            #pragma unroll
            for (int r = 0; r < 4; ++r)
                wq[h][r] = WaggN[(4*g + r)*Hh + h];
    }
    float wpa[4] = {0,0,0,0}, wpb[4] = {0,0,0,0}, bp0 = 0.f, bp1 = 0.f;
    if (LAST) {
        f32x4 u0 = *reinterpret_cast<const f32x4*>(Wp + 8*g);
        f32x4 u1 = *reinterpret_cast<const f32x4*>(Wp + 8*g + 4);
        wpa[0]=u0[0]; wpa[1]=u0[2]; wpa[2]=u1[0]; wpa[3]=u1[2];
        wpb[0]=u0[1]; wpb[1]=u0[3]; wpb[2]=u1[1]; wpb[3]=u1[3];
        bp0 = bp[0]; bp1 = bp[1];
    }
    float wacc[Hh] = {0,0,0,0,0,0,0};
    float wcnt = 0.f;
    __syncthreads();

    size_t r0 = (size_t)(blockIdx.x*16 + wave*4) * 16;

    // ---- prefetch all 4 tiles' inputs ----
    BF8 bz_; bz_.u[0]=bz_.u[1]=bz_.u[2]=bz_.u[3]=0u;
    if (g == 2) bz_.u[0] = 0x00003F80u;          // k=16 slot = 1.0 (bias mult)
    bf16x8 bx0 = bz_.v, bx1 = bz_.v, bx2 = bz_.v, bx3 = bz_.v;
    if (g < 2) {
        const unsigned short* xp = Xe + (r0 + i)*Ee + g*8;
        bx0 = *reinterpret_cast<const bf16x8*>(xp);
        bx1 = *reinterpret_cast<const bf16x8*>(xp + 16*Ee);
        bx2 = *reinterpret_cast<const bf16x8*>(xp + 32*Ee);
        bx3 = *reinterpret_cast<const bf16x8*>(xp + 48*Ee);
    }
    const unsigned short* zp = Zin + (r0 + i)*Ee + 4*g;
    u32x2 zu0 = *reinterpret_cast<const u32x2*>(zp);
    u32x2 zu1 = *reinterpret_cast<const u32x2*>(zp + 16*Ee);
    u32x2 zu2 = *reinterpret_cast<const u32x2*>(zp + 32*Ee);
    u32x2 zu3 = *reinterpret_cast<const u32x2*>(zp + 48*Ee);

    unsigned short* p1A = &sP1[wave][0][0];
    unsigned short* p1B = &sP1[wave][1][0];
    const f32x4 zz = {0.f,0.f,0.f,0.f};

    auto epi = [&](const f32x4* d2, u32x2 zu, size_t row0) {
        float s = 0.f;
        #pragma unroll
        for (int mt = 0; mt < 7; ++mt) s += d2[mt][0]+d2[mt][1]+d2[mt][2]+d2[mt][3];
        s += __shfl_xor(s, 16); s += __shfl_xor(s, 32);
        float m = s * (1.f/EH);
        float q = 0.f;
        #pragma unroll
        for (int mt = 0; mt < 7; ++mt) {
            #pragma unroll
            for (int r = 0; r < 4; ++r) { float dd = d2[mt][r]-m; q = fmaf(dd,dd,q); }
        }
        q += __shfl_xor(q, 16); q += __shfl_xor(q, 32);
        float inv = rsqrtf(q*(1.f/EH) + 1e-6f);

        float S1[4] = {0,0,0,0};
        #pragma unroll
        for (int mt = 0; mt < 7; ++mt) {
            #pragma unroll
            for (int r = 0; r < 4; ++r) S1[r] = fmaf(d2[mt][r], gz[mt][r], S1[r]);
        }
        unsigned lo = zu[0], hi = zu[1];
        float zv[4];
        zv[0] = __uint_as_float((lo & 0xFFFFu) << 16);
        zv[1] = __uint_as_float(lo & 0xFFFF0000u);
        zv[2] = __uint_as_float((hi & 0xFFFFu) << 16);
        zv[3] = __uint_as_float(hi & 0xFFFF0000u);
        float zn[4];
        #pragma unroll
        for (int r = 0; r < 4; ++r)
            zn[r] = zv[r] + (fmaf(-m, Gz[r], S1[r]) * inv + Bz[r]);

        if (!LAST) {
            u32x2 w = {pack2(zn[0], zn[1]), pack2(zn[2], zn[3])};
            *reinterpret_cast<u32x2*>(Zout + (row0 + i)*Ee + 4*g) = w;
            // fused zbar partials for next depth
            float af = (float)avail[row0 + i];
            float z20 = zn[0]*zn[0], z21 = zn[1]*zn[1];
            float z22 = zn[2]*zn[2], z23 = zn[3]*zn[3];
            #pragma unroll
            for (int h = 0; h < Hh; ++h) {
                float f = z20*wq[h][0] + z21*wq[h][1] + z22*wq[h][2] + z23*wq[h][3];
                f += __shfl_xor(f, 16); f += __shfl_xor(f, 32);
                wacc[h] = fmaf(af, f, wacc[h]);
            }
            wcnt += af;
        } else {
            float o0 = zn[0]*wpa[0] + zn[1]*wpa[1] + zn[2]*wpa[2] + zn[3]*wpa[3];
            float o1 = zn[0]*wpb[0] + zn[1]*wpb[1] + zn[2]*wpb[2] + zn[3]*wpb[3];
            o0 += __shfl_xor(o0, 16); o0 += __shfl_xor(o0, 32);
            o1 += __shfl_xor(o1, 16); o1 += __shfl_xor(o1, 32);
            if (g == 0) {
                float2 o; o.x = o0 + bp0; o.y = o1 + bp1;
                *reinterpret_cast<float2*>(out + (row0 + i)*2) = o;
            }
        }
    };

    auto pair = [&](bf16x8 bxA, bf16x8 bxB, u32x2 zuA, u32x2 zuB, size_t rowA) {
        // phi1 both tiles (A-frag shared)
        #pragma unroll
        for (int mt = 0; mt < 7; ++mt) {
            f32x4 dA = __builtin_amdgcn_mfma_f32_16x16x32_bf16(aW1[mt], bxA, zz, 0,0,0);
            f32x4 dB = __builtin_amdgcn_mfma_f32_16x16x32_bf16(aW1[mt], bxB, zz, 0,0,0);
            #pragma unroll
            for (int r = 0; r < 4; ++r) { dA[r] = fmaxf(dA[r],0.f); dB[r] = fmaxf(dB[r],0.f); }
            u32x2 wA = {pack2(dA[0],dA[1]), pack2(dA[2],dA[3])};
            u32x2 wB = {pack2(dB[0],dB[1]), pack2(dB[2],dB[3])};
            *reinterpret_cast<u32x2*>(&p1A[i*PS + mt*16 + 4*g]) = wA;
            *reinterpret_cast<u32x2*>(&p1B[i*PS + mt*16 + 4*g]) = wB;
        }
        // phi2 both tiles (W2 A-frag read once, used twice)
        f32x4 d2A[7], d2B[7];
        #pragma unroll
        for (int mt = 0; mt < 7; ++mt) { d2A[mt] = zz; d2B[mt] = zz; }
        #pragma unroll
        for (int kt = 0; kt < 4; ++kt) {
            bf16x8 bpA = *reinterpret_cast<const bf16x8*>(&p1A[i*PS + kt*32 + 8*g]);
            bf16x8 bpB = *reinterpret_cast<const bf16x8*>(&p1B[i*PS + kt*32 + 8*g]);
            #pragma unroll
            for (int mt = 0; mt < 7; ++mt) {
                bf16x8 a = *reinterpret_cast<const bf16x8*>(&sW2F[(mt*4 + kt)*512 + lane*8]);
                d2A[mt] = __builtin_amdgcn_mfma_f32_16x16x32_bf16(a, bpA, d2A[mt], 0,0,0);
                d2B[mt] = __builtin_amdgcn_mfma_f32_16x16x32_bf16(a, bpB, d2B[mt], 0,0,0);
            }
        }
        epi(d2A, zuA, rowA);
        epi(d2B, zuB, rowA + 16);
    };

    pair(bx0, bx1, zu0, zu1, r0);
    pair(bx2, bx3, zu2, zu3, r0 + 32);

    if (!LAST) {
        #pragma unroll
        for (int off = 1; off < 64; off <<= 1) {
            #pragma unroll
            for (int h = 0; h < Hh; ++h) wacc[h] += __shfl_xor(wacc[h], off);
            wcnt += __shfl_xor(wcnt, off);
        }
        if (lane == 0) {
            #pragma unroll
            for (int h = 0; h < Hh; ++h) sRed[wave][h] = wacc[h]*0.25f;
            sRed[wave][7] = wcnt*0.25f;
        }
        __syncthreads();
        if (tid < 8)
            atomicAdd(&accN[b*8 + tid],
                      sRed[0][tid]+sRed[1][tid]+sRed[2][tid]+sRed[3][tid]);
    }
}

// ---------------------------------------------------------------- launcher --
extern "C" void kernel_launch(void* const* d_in, const int* in_sizes, int n_in,
                              void* d_out, int out_size, void* d_ws, size_t ws_size,
                              hipStream_t stream)
{
    const float* X      = (const float*)d_in[0];
    const int*   avail  = (const int*)  d_in[1];
    const float* W_enc1 = (const float*)d_in[2];  const float* b_enc1 = (const float*)d_in[3];
    const float* W_enc2 = (const float*)d_in[4];  const float* b_enc2 = (const float*)d_in[5];
    const float* W_enc3 = (const float*)d_in[6];  const float* b_enc3 = (const float*)d_in[7];
    const float* g_enc  = (const float*)d_in[8];  const float* be_enc = (const float*)d_in[9];
    const float* W_agg  = (const float*)d_in[10]; const float* b_agg  = (const float*)d_in[11];
    const float* W_phi1 = (const float*)d_in[12]; const float* b_phi1 = (const float*)d_in[13];
    const float* W_phi2 = (const float*)d_in[14]; const float* b_phi2 = (const float*)d_in[15];
    const float* g_phi  = (const float*)d_in[16]; const float* be_phi = (const float*)d_in[17];
    const float* W_proj = (const float*)d_in[18]; const float* b_proj = (const float*)d_in[19];
    float* out = (float*)d_out;

    char* ws = (char*)d_ws;
    unsigned short* XeBF = (unsigned short*)ws;                    // 16 MiB
    unsigned short* Zb   = (unsigned short*)(ws + (size_t)NROW*Ee*2);  // 16 MiB
    char* p = ws + 2*(size_t)NROW*Ee*2;
    float* acc = (float*)p;                  p += 3*Bb*8*sizeof(float);
    unsigned short* W2F = (unsigned short*)p; p += (size_t)3*28*512*2;
    unsigned short* W1F = (unsigned short*)p;

    hipMemsetAsync(acc, 0, 3*Bb*8*sizeof(float), stream);
    wpack<<<(3*28*64 + 3*7*64 + 255)/256, 256, 0, stream>>>(
        W_phi2, W_phi1, b_phi1, b_phi2, W2F, W1F);

    enc_kernel<<<NBLK, 256, 0, stream>>>(
        X, W_enc1, b_enc1, W_enc2, b_enc2, W_enc3, b_enc3, g_enc, be_enc,
        W_agg, avail, XeBF, acc);

    phi_mfma<false><<<NBLK, 256, 0, stream>>>(
        XeBF, XeBF, Zb, acc, b_agg, W_agg + Ee*Hh, acc + Bb*8, avail,
        W1F, W2F, g_phi, be_phi, W_proj, b_proj, out);

    phi_mfma<false><<<NBLK, 256, 0, stream>>>(
        Zb, XeBF, Zb, acc + Bb*8, b_agg + Hh, W_agg + 2*Ee*Hh, acc + 2*Bb*8, avail,
        W1F + (size_t)7*512, W2F + (size_t)28*512,
        g_phi + EH, be_phi + EH, W_proj, b_proj, out);

    phi_mfma<true><<<NBLK, 256, 0, stream>>>(
        Zb, XeBF, Zb, acc + 2*Bb*8, b_agg + 2*Hh, W_agg, acc, avail,
        W1F + (size_t)14*512, W2F + (size_t)56*512,
        g_phi + 2*EH, be_phi + 2*EH, W_proj, b_proj, out);
}